// Round 2
// baseline (167.123 us; speedup 1.0000x reference)
//
#include <hip/hip_runtime.h>
#include <stdint.h>
#include <stddef.h>

// ---------------------------------------------------------------------------
// StructureAwareAttention  (B=2, L=1024, D=1024, H=16, HD=64)
//   qkv = x@Wqkv + bqkv            -> q,k [B,H,L,64] bf16, v^T [B,H,64,L] bf16
//   sw  = sb@Ws + bs               -> f32 [B,L,L]
//   attn = softmax(q k^T / 8 + sw) ; ctx = attn @ v  -> bf16 [B,L,D]
//   out = ctx@Wo + bo              -> f32 [B,L,D]
// All GEMMs: bf16 MFMA 16x16x32, f32 accum. Workspace layout (bytes):
//   0: xb 4MB | 4MB: sbb 4MB | 8MB: Wqkv^T 6MB | 14MB: Ws^T 2MB | 16MB: Wo^T 2MB
//   18MB: q 4MB | 22MB: k 4MB | 26MB: v^T 4MB | 30MB: sw(f32) 8MB | 38MB: ctx 4MB
//   total 42MB (assumes ws_size >= 42MB)
// ---------------------------------------------------------------------------

typedef float f32x4 __attribute__((ext_vector_type(4)));
typedef short s16x8 __attribute__((ext_vector_type(8)));
typedef unsigned short u16x8 __attribute__((ext_vector_type(8)));
typedef unsigned short u16x4 __attribute__((ext_vector_type(4)));

__device__ inline unsigned short f2bf(float f) {          // RNE f32 -> bf16
    unsigned u = __builtin_bit_cast(unsigned, f);
    u += 0x7fffu + ((u >> 16) & 1u);
    return (unsigned short)(u >> 16);
}

__device__ inline f32x4 mfma16(s16x8 a, s16x8 b, f32x4 c) {
    return __builtin_amdgcn_mfma_f32_16x16x32_bf16(a, b, c, 0, 0, 0);
}

__device__ inline void gld_lds16(const void* g, const void* lds_base) {
    // async global->LDS, 16B per lane, dest = wave-uniform base + lane*16
    __builtin_amdgcn_global_load_lds(
        (const __attribute__((address_space(1))) void*)(uintptr_t)g,
        (__attribute__((address_space(3))) void*)(unsigned)(uintptr_t)lds_base,
        16, 0, 0);
}

// -------------------------------- convert ----------------------------------
__global__ void cvt_bf16_k(const float* __restrict__ src, unsigned short* __restrict__ dst) {
    int i = blockIdx.x * 256 + threadIdx.x;          // each thread: 8 f32 -> 8 bf16
    const float4* s4 = (const float4*)src;
    float4 a = s4[2 * i], b = s4[2 * i + 1];
    u16x8 o;
    o[0] = f2bf(a.x); o[1] = f2bf(a.y); o[2] = f2bf(a.z); o[3] = f2bf(a.w);
    o[4] = f2bf(b.x); o[5] = f2bf(b.y); o[6] = f2bf(b.z); o[7] = f2bf(b.w);
    *(u16x8*)(dst + (size_t)i * 8) = o;
}

// ---------------------- weight transpose: W[K][N] -> Wt[N][K] bf16 ----------
__global__ __launch_bounds__(256) void transpose_w_k(const float* __restrict__ W,
                                                     unsigned short* __restrict__ Wt, int N) {
    __shared__ float tile[64][65];
    const int t = threadIdx.x;
    const int n0 = blockIdx.x * 64, k0 = blockIdx.y * 64;
    const int lr = t >> 4, lc = (t & 15) * 4;
#pragma unroll
    for (int rr = 0; rr < 4; rr++) {
        int r = lr + rr * 16;
        float4 v = *(const float4*)(W + (size_t)(k0 + r) * N + n0 + lc);
        tile[r][lc] = v.x; tile[r][lc + 1] = v.y; tile[r][lc + 2] = v.z; tile[r][lc + 3] = v.w;
    }
    __syncthreads();
    const int wn = t >> 3, wk = (t & 7) * 8;
#pragma unroll
    for (int rr = 0; rr < 2; rr++) {
        int n = wn + rr * 32;
        u16x8 o;
#pragma unroll
        for (int j = 0; j < 8; j++) o[j] = f2bf(tile[wk + j][n]);
        *(u16x8*)(Wt + (size_t)(n0 + n) * 1024 + k0 + wk) = o;
    }
}

// ------------------------------- GEMM --------------------------------------
// C[M,N] = A[M,1024] @ Bt[N,1024]^T + bias.  128x128 tile, BK=32, 4 waves.
// EPI 0: scatter bf16 into q/k [B,H,L,64] and v^T [B,H,64,L] (N=3072)
// EPI 1: f32 row-major [M][1024]
template <int EPI>
__global__ __launch_bounds__(256) void gemm_k(const unsigned short* __restrict__ A,
                                              const unsigned short* __restrict__ Bt,
                                              const float* __restrict__ bias,
                                              unsigned short* __restrict__ q,
                                              unsigned short* __restrict__ kk_,
                                              unsigned short* __restrict__ vt,
                                              float* __restrict__ outf) {
    __shared__ unsigned short lA[4096], lB[4096];   // 128 x 32 bf16 each
    const int t = threadIdx.x;
    const int wave = t >> 6, lane = t & 63, c = lane & 15, g = lane >> 4;
    const int bn0 = blockIdx.x * 128, bm0 = blockIdx.y * 128;
    const int wr = (wave >> 1) * 64, wc = (wave & 1) * 64;
    // staging map: slot s -> row=s>>2, phys chunk p=s&3 holds logical chunk p^((row>>1)&3)
    const int row = t >> 2, p = t & 3;
    const int gg = p ^ ((row >> 1) & 3);
    const size_t aoff = (size_t)(bm0 + row) * 1024 + gg * 8;
    const size_t boff = (size_t)(bn0 + row) * 1024 + gg * 8;
    char* lAb = (char*)lA; char* lBb = (char*)lB;

    f32x4 acc[4][4];
#pragma unroll
    for (int i = 0; i < 4; i++)
#pragma unroll
        for (int j = 0; j < 4; j++) acc[i][j] = {0.f, 0.f, 0.f, 0.f};

    for (int kt = 0; kt < 1024; kt += 32) {
        __syncthreads();
        gld_lds16(A + aoff + kt,                      lAb + wave * 1024);
        gld_lds16(A + aoff + (size_t)64 * 1024 + kt,  lAb + 4096 + wave * 1024);
        gld_lds16(Bt + boff + kt,                     lBb + wave * 1024);
        gld_lds16(Bt + boff + (size_t)64 * 1024 + kt, lBb + 4096 + wave * 1024);
        __syncthreads();
        s16x8 af[4], bfr[4];
#pragma unroll
        for (int i = 0; i < 4; i++) {
            int r_ = wr + i * 16 + c;
            af[i] = *(const s16x8*)(lAb + r_ * 64 + ((g ^ ((r_ >> 1) & 3)) << 4));
        }
#pragma unroll
        for (int j = 0; j < 4; j++) {
            int r_ = wc + j * 16 + c;
            bfr[j] = *(const s16x8*)(lBb + r_ * 64 + ((g ^ ((r_ >> 1) & 3)) << 4));
        }
#pragma unroll
        for (int i = 0; i < 4; i++)
#pragma unroll
            for (int j = 0; j < 4; j++)
                acc[i][j] = mfma16(af[i], bfr[j], acc[i][j]);
    }

#pragma unroll
    for (int i = 0; i < 4; i++) {
#pragma unroll
        for (int j = 0; j < 4; j++) {
            const int n = bn0 + wc + j * 16 + c;
            const float bv = bias[n];
#pragma unroll
            for (int r = 0; r < 4; r++) {
                const int m = bm0 + wr + i * 16 + g * 4 + r;
                float v = acc[i][j][r] + bv;
                if (EPI == 0) {
                    const int sel = n >> 10, h = (n >> 6) & 15, d = n & 63;
                    const int b_ = m >> 10, l_ = m & 1023;
                    const size_t bh = (size_t)((b_ << 4) + h);
                    unsigned short hv = f2bf(v);
                    if (sel == 0)      q[(bh * 1024 + l_) * 64 + d] = hv;
                    else if (sel == 1) kk_[(bh * 1024 + l_) * 64 + d] = hv;
                    else               vt[(bh * 64 + d) * 1024 + l_] = hv;
                } else {
                    outf[(size_t)m * 1024 + n] = v;
                }
            }
        }
    }
}

// ------------------------------ attention ----------------------------------
// 1 block = (b,h, 64 q-rows); wave w owns 16 q-rows. KVBLK=32.
// SWAPPED QK^T: S^T = mfma(K_frag, Q_frag) so lane (c=q, g) holds 8 scores of
// q-row c -> row-reduce is 7 lane-local ops + 2 shfl_xor. Online softmax in
// exp2 domain; P transposed to A-frag via per-wave padded LDS tile (b64
// writes); rescale factor f broadcast via 16-float LDS line (b128 broadcast).
__global__ __launch_bounds__(256) void attn_k(const unsigned short* __restrict__ q,
                                              const unsigned short* __restrict__ k,
                                              const unsigned short* __restrict__ vt,
                                              const float* __restrict__ sw,
                                              unsigned short* __restrict__ ctx) {
    __shared__ unsigned short lP[4][640];            // per wave: 16 q-rows x 40 (pad)
    __shared__ float lF[4][16];                      // per wave: f / inv broadcast
    const int t = threadIdx.x, wave = t >> 6, lane = t & 63, c = lane & 15, g = lane >> 4;
    const int blk = blockIdx.x;
    const int qt = blk & 15, bh = blk >> 4, b_ = bh >> 4, h = bh & 15;
    const int qr = qt * 64 + wave * 16;

    // Q as B-operand: lane holds Q[q=c][hd = g*8..g*8+7] and [32+g*8 ..]
    const unsigned short* qbase = q + ((size_t)bh * 1024 + qr) * 64;
    s16x8 qf0 = *(const s16x8*)(qbase + (size_t)c * 64 + g * 8);
    s16x8 qf1 = *(const s16x8*)(qbase + (size_t)c * 64 + 32 + g * 8);

    const unsigned short* kb0 = k + (size_t)bh * 1024 * 64;
    const unsigned short* vb0 = vt + (size_t)bh * 64 * 1024;
    const float* swrow = sw + ((size_t)b_ * 1024 + qr + c) * 1024;   // row of q=c
    unsigned short* wp = lP[wave];
    float* wf = lF[wave];

    const float SC  = 0.125f * 1.4426950408889634f;  // (1/sqrt(64)) * log2(e)
    const float L2E = 1.4426950408889634f;

    float mr = -1e30f, lr = 0.0f;    // online state for q-row c (replicated over g)
    f32x4 acc[4];                    // acc[nf][r] = ctx[q = g*4+r][d = nf*16+c]
#pragma unroll
    for (int nf = 0; nf < 4; nf++) acc[nf] = {0.f, 0.f, 0.f, 0.f};

    for (int kv0 = 0; kv0 < 1024; kv0 += 32) {
        // independent loads first (overlap with softmax chain of prev/this iter)
        float4 swa = *(const float4*)(swrow + kv0 + 4 * g);
        float4 swb = *(const float4*)(swrow + kv0 + 16 + 4 * g);
        const unsigned short* kb = kb0 + (size_t)kv0 * 64;
        s16x8 k00 = *(const s16x8*)(kb + c * 64 + g * 8);
        s16x8 k01 = *(const s16x8*)(kb + c * 64 + 32 + g * 8);
        s16x8 k10 = *(const s16x8*)(kb + (16 + c) * 64 + g * 8);
        s16x8 k11 = *(const s16x8*)(kb + (16 + c) * 64 + 32 + g * 8);
        s16x8 vf[4];
#pragma unroll
        for (int nf = 0; nf < 4; nf++)
            vf[nf] = *(const s16x8*)(vb0 + (size_t)(nf * 16 + c) * 1024 + kv0 + g * 8);

        // S^T: lane (c,g): s0[r] = S[k=kv0+4g+r][q=c], s1[r] = S[k=kv0+16+4g+r][q=c]
        f32x4 s0 = {0.f, 0.f, 0.f, 0.f}, s1 = {0.f, 0.f, 0.f, 0.f};
        s0 = mfma16(k00, qf0, s0); s0 = mfma16(k01, qf1, s0);
        s1 = mfma16(k10, qf0, s1); s1 = mfma16(k11, qf1, s1);

        float z0[4], z1[4];
#pragma unroll
        for (int r = 0; r < 4; r++) {
            z0[r] = s0[r] * SC + (&swa.x)[r] * L2E;
            z1[r] = s1[r] * SC + (&swb.x)[r] * L2E;
        }
        float tm = fmaxf(fmaxf(fmaxf(z0[0], z0[1]), fmaxf(z0[2], z0[3])),
                         fmaxf(fmaxf(z1[0], z1[1]), fmaxf(z1[2], z1[3])));
        tm = fmaxf(tm, __shfl_xor(tm, 16, 64));
        tm = fmaxf(tm, __shfl_xor(tm, 32, 64));

        bool grow = (tm > mr);
        float mn = grow ? tm : mr;                   // == fmaxf(mr, tm)
        float p0[4], p1[4];
#pragma unroll
        for (int r = 0; r < 4; r++) {
            p0[r] = __builtin_amdgcn_exp2f(z0[r] - mn);
            p1[r] = __builtin_amdgcn_exp2f(z1[r] - mn);
        }
        float rs = (p0[0] + p0[1]) + (p0[2] + p0[3]) + (p1[0] + p1[1]) + (p1[2] + p1[3]);
        rs += __shfl_xor(rs, 16, 64);
        rs += __shfl_xor(rs, 32, 64);

        if (__any((int)grow)) {                      // some q-row's max advanced
            float f = __builtin_amdgcn_exp2f(mr - mn);
            mr = mn;
            lr = lr * f + rs;
            if (g == 0) wf[c] = f;
            f32x4 fv = *(const f32x4*)(wf + g * 4);  // f for q = g*4+r (broadcast)
#pragma unroll
            for (int nf = 0; nf < 4; nf++)
#pragma unroll
                for (int r = 0; r < 4; r++) acc[nf][r] *= fv[r];
        } else {                                     // exact: f == 1 everywhere
            lr += rs;
        }

        // P -> LDS transpose: lane owns (q=c, k=4g..4g+3) and (q=c, k=16+4g..)
        u16x4 w0, w1;
#pragma unroll
        for (int r = 0; r < 4; r++) { w0[r] = f2bf(p0[r]); w1[r] = f2bf(p1[r]); }
        *(u16x4*)(wp + c * 40 + 4 * g) = w0;
        *(u16x4*)(wp + c * 40 + 16 + 4 * g) = w1;

        // A-frag: lane holds P[q=c][k = g*8 .. g*8+7]
        s16x8 ap = *(const s16x8*)((const char*)wp + c * 80 + g * 16);
#pragma unroll
        for (int nf = 0; nf < 4; nf++)
            acc[nf] = mfma16(ap, vf[nf], acc[nf]);
    }

    if (g == 0) wf[c] = 1.0f / lr;
    f32x4 inv = *(const f32x4*)(wf + g * 4);         // inv for q = g*4+r
#pragma unroll
    for (int nf = 0; nf < 4; nf++) {
#pragma unroll
        for (int r = 0; r < 4; r++) {
            const size_t orow = ((size_t)b_ * 1024 + qr + 4 * g + r) * 1024 + h * 64;
            ctx[orow + nf * 16 + c] = f2bf(acc[nf][r] * inv[r]);
        }
    }
}

// ------------------------------- launch ------------------------------------
extern "C" void kernel_launch(void* const* d_in, const int* in_sizes, int n_in,
                              void* d_out, int out_size, void* d_ws, size_t ws_size,
                              hipStream_t stream) {
    const float* x    = (const float*)d_in[0];
    const float* sb   = (const float*)d_in[1];
    const float* Wqkv = (const float*)d_in[2];
    const float* bqkv = (const float*)d_in[3];
    const float* Ws   = (const float*)d_in[4];
    const float* bs   = (const float*)d_in[5];
    const float* Wo   = (const float*)d_in[6];
    const float* bo   = (const float*)d_in[7];
    float* out = (float*)d_out;

    char* ws = (char*)d_ws;
    unsigned short* xb    = (unsigned short*)(ws);
    unsigned short* sbb   = (unsigned short*)(ws + ((size_t)4 << 20));
    unsigned short* wqkvt = (unsigned short*)(ws + ((size_t)8 << 20));
    unsigned short* wst   = (unsigned short*)(ws + ((size_t)14 << 20));
    unsigned short* wot   = (unsigned short*)(ws + ((size_t)16 << 20));
    unsigned short* qb    = (unsigned short*)(ws + ((size_t)18 << 20));
    unsigned short* kb    = (unsigned short*)(ws + ((size_t)22 << 20));
    unsigned short* vtb   = (unsigned short*)(ws + ((size_t)26 << 20));
    float*          swf   = (float*)        (ws + ((size_t)30 << 20));
    unsigned short* ctxb  = (unsigned short*)(ws + ((size_t)38 << 20));

    cvt_bf16_k<<<dim3(1024), dim3(256), 0, stream>>>(x, xb);
    cvt_bf16_k<<<dim3(1024), dim3(256), 0, stream>>>(sb, sbb);
    transpose_w_k<<<dim3(48, 16), dim3(256), 0, stream>>>(Wqkv, wqkvt, 3072);
    transpose_w_k<<<dim3(16, 16), dim3(256), 0, stream>>>(Ws, wst, 1024);
    transpose_w_k<<<dim3(16, 16), dim3(256), 0, stream>>>(Wo, wot, 1024);
    gemm_k<0><<<dim3(24, 16), dim3(256), 0, stream>>>(xb, wqkvt, bqkv, qb, kb, vtb, (float*)nullptr);
    gemm_k<1><<<dim3(8, 16), dim3(256), 0, stream>>>(sbb, wst, bs,
                                                     (unsigned short*)nullptr, (unsigned short*)nullptr,
                                                     (unsigned short*)nullptr, swf);
    attn_k<<<dim3(512), dim3(256), 0, stream>>>(qb, kb, vtb, swf, ctxb);
    gemm_k<1><<<dim3(8, 16), dim3(256), 0, stream>>>(ctxb, wot, bo,
                                                     (unsigned short*)nullptr, (unsigned short*)nullptr,
                                                     (unsigned short*)nullptr, out);
}

// Round 3
// 164.328 us; speedup vs baseline: 1.0170x; 1.0170x over previous
//
#include <hip/hip_runtime.h>
#include <stdint.h>
#include <stddef.h>

// ---------------------------------------------------------------------------
// StructureAwareAttention  (B=2, L=1024, D=1024, H=16, HD=64)
//   qkv = x@Wqkv + bqkv            -> q,k [B,H,L,64] bf16, v^T [B,H,64,L] bf16
//   sw  = sb@Ws + bs               -> f32 [B,L,L]
//   attn: split-KV(2) flash, swapped QK^T and swapped PV (all state lane-local)
//   combine partials -> ctx bf16 [B,L,D];  out = ctx@Wo + bo -> f32
// Workspace (bytes):
//   0..16MB : partial ctx^T f32 [2][512][64][64]   (reuses xb/sbb/wqkvt/wst)
//   0: xb 4MB | 4MB: sbb 4MB | 8MB: Wqkv^T 6MB | 14MB: Ws^T 2MB   (early stage)
//   16MB: Wo^T 2MB | 18MB: q 4MB | 22MB: k 4MB | 26MB: v^T 4MB
//   30MB: sw(f32) 8MB | 38MB: ctx 4MB | 42MB: ml f32 [2][512][64][2] 0.5MB
// ---------------------------------------------------------------------------

typedef float f32x4 __attribute__((ext_vector_type(4)));
typedef short s16x8 __attribute__((ext_vector_type(8)));
typedef unsigned short u16x8 __attribute__((ext_vector_type(8)));
typedef unsigned short u16x4 __attribute__((ext_vector_type(4)));

__device__ inline unsigned short f2bf(float f) {          // RNE f32 -> bf16
    unsigned u = __builtin_bit_cast(unsigned, f);
    u += 0x7fffu + ((u >> 16) & 1u);
    return (unsigned short)(u >> 16);
}

__device__ inline f32x4 mfma16(s16x8 a, s16x8 b, f32x4 c) {
    return __builtin_amdgcn_mfma_f32_16x16x32_bf16(a, b, c, 0, 0, 0);
}

__device__ inline void gld_lds16(const void* g, const void* lds_base) {
    __builtin_amdgcn_global_load_lds(
        (const __attribute__((address_space(1))) void*)(uintptr_t)g,
        (__attribute__((address_space(3))) void*)(unsigned)(uintptr_t)lds_base,
        16, 0, 0);
}

// -------------------------------- convert ----------------------------------
__global__ void cvt_bf16_k(const float* __restrict__ src, unsigned short* __restrict__ dst) {
    int i = blockIdx.x * 256 + threadIdx.x;
    const float4* s4 = (const float4*)src;
    float4 a = s4[2 * i], b = s4[2 * i + 1];
    u16x8 o;
    o[0] = f2bf(a.x); o[1] = f2bf(a.y); o[2] = f2bf(a.z); o[3] = f2bf(a.w);
    o[4] = f2bf(b.x); o[5] = f2bf(b.y); o[6] = f2bf(b.z); o[7] = f2bf(b.w);
    *(u16x8*)(dst + (size_t)i * 8) = o;
}

// ---------------------- weight transpose: W[K][N] -> Wt[N][K] bf16 ----------
__global__ __launch_bounds__(256) void transpose_w_k(const float* __restrict__ W,
                                                     unsigned short* __restrict__ Wt, int N) {
    __shared__ float tile[64][65];
    const int t = threadIdx.x;
    const int n0 = blockIdx.x * 64, k0 = blockIdx.y * 64;
    const int lr = t >> 4, lc = (t & 15) * 4;
#pragma unroll
    for (int rr = 0; rr < 4; rr++) {
        int r = lr + rr * 16;
        float4 v = *(const float4*)(W + (size_t)(k0 + r) * N + n0 + lc);
        tile[r][lc] = v.x; tile[r][lc + 1] = v.y; tile[r][lc + 2] = v.z; tile[r][lc + 3] = v.w;
    }
    __syncthreads();
    const int wn = t >> 3, wk = (t & 7) * 8;
#pragma unroll
    for (int rr = 0; rr < 2; rr++) {
        int n = wn + rr * 32;
        u16x8 o;
#pragma unroll
        for (int j = 0; j < 8; j++) o[j] = f2bf(tile[wk + j][n]);
        *(u16x8*)(Wt + (size_t)(n0 + n) * 1024 + k0 + wk) = o;
    }
}

// ------------------------------- GEMM --------------------------------------
// C[M,N] = A[M,1024] @ Bt[N,1024]^T + bias.  BM x BN tile, BK=32, 4 waves.
// (BM,BN) in {(128,128),(64,128),(128,64)}.
// EPI 0: scatter bf16 into q/k [B,H,L,64] and v^T [B,H,64,L] (N=3072)
// EPI 1: f32 row-major [M][1024]
template <int EPI, int BM, int BN>
__global__ __launch_bounds__(256) void gemm_k(const unsigned short* __restrict__ A,
                                              const unsigned short* __restrict__ Bt,
                                              const float* __restrict__ bias,
                                              unsigned short* __restrict__ q,
                                              unsigned short* __restrict__ kk_,
                                              unsigned short* __restrict__ vt,
                                              float* __restrict__ outf) {
    __shared__ unsigned short lA[BM * 32], lB[BN * 32];
    const int t = threadIdx.x;
    const int wave = t >> 6, lane = t & 63, c = lane & 15, g = lane >> 4;
    const int bn0 = blockIdx.x * BN, bm0 = blockIdx.y * BM;
    constexpr int MI = (BN == 64) ? 2 : 4;
    constexpr int NI = (BN == 64) ? 4 : (BM == 64 ? 2 : 4);
    int wr, wc;
    if (BM == 64)      { wr = 0;                wc = wave * 32; }
    else if (BN == 64) { wr = wave * 32;        wc = 0; }
    else               { wr = (wave >> 1) * 64; wc = (wave & 1) * 64; }
    // staging map: slot s -> row=s>>2, phys chunk p=s&3 holds logical chunk p^((row>>1)&3)
    const int row = t >> 2, p = t & 3;
    const int gg = p ^ ((row >> 1) & 3);
    const size_t aoff = (size_t)(bm0 + row) * 1024 + gg * 8;
    const size_t boff = (size_t)(bn0 + row) * 1024 + gg * 8;
    char* lAb = (char*)lA; char* lBb = (char*)lB;

    f32x4 acc[MI][NI];
#pragma unroll
    for (int i = 0; i < MI; i++)
#pragma unroll
        for (int j = 0; j < NI; j++) acc[i][j] = {0.f, 0.f, 0.f, 0.f};

    for (int kt = 0; kt < 1024; kt += 32) {
        __syncthreads();
#pragma unroll
        for (int h = 0; h < BM / 64; h++)
            gld_lds16(A + aoff + (size_t)h * 64 * 1024 + kt, lAb + h * 4096 + wave * 1024);
#pragma unroll
        for (int h = 0; h < BN / 64; h++)
            gld_lds16(Bt + boff + (size_t)h * 64 * 1024 + kt, lBb + h * 4096 + wave * 1024);
        __syncthreads();
        s16x8 af[MI], bfr[NI];
#pragma unroll
        for (int i = 0; i < MI; i++) {
            int r_ = wr + i * 16 + c;
            af[i] = *(const s16x8*)(lAb + r_ * 64 + ((g ^ ((r_ >> 1) & 3)) << 4));
        }
#pragma unroll
        for (int j = 0; j < NI; j++) {
            int r_ = wc + j * 16 + c;
            bfr[j] = *(const s16x8*)(lBb + r_ * 64 + ((g ^ ((r_ >> 1) & 3)) << 4));
        }
#pragma unroll
        for (int i = 0; i < MI; i++)
#pragma unroll
            for (int j = 0; j < NI; j++)
                acc[i][j] = mfma16(af[i], bfr[j], acc[i][j]);
    }

#pragma unroll
    for (int i = 0; i < MI; i++) {
#pragma unroll
        for (int j = 0; j < NI; j++) {
            const int n = bn0 + wc + j * 16 + c;
            const float bv = bias[n];
#pragma unroll
            for (int r = 0; r < 4; r++) {
                const int m = bm0 + wr + i * 16 + g * 4 + r;
                float v = acc[i][j][r] + bv;
                if (EPI == 0) {
                    const int sel = n >> 10, h = (n >> 6) & 15, d = n & 63;
                    const int b_ = m >> 10, l_ = m & 1023;
                    const size_t bh = (size_t)((b_ << 4) + h);
                    unsigned short hv = f2bf(v);
                    if (sel == 0)      q[(bh * 1024 + l_) * 64 + d] = hv;
                    else if (sel == 1) kk_[(bh * 1024 + l_) * 64 + d] = hv;
                    else               vt[(bh * 64 + d) * 1024 + l_] = hv;
                } else {
                    outf[(size_t)m * 1024 + n] = v;
                }
            }
        }
    }
}

// ------------------------------ attention ----------------------------------
// grid (512, 2): blockIdx.x = bh*16+qt, blockIdx.y = KV half. Wave w owns 16
// q-rows; KVBLK=32, 16 iters. Swapped QK^T (S^T = mfma(K,Q)) AND swapped PV
// (ctx^T = mfma(V^T, P^T)) -> softmax state m,l and rescale fully lane-local.
// K + sw register double-buffered (prefetch next iter before softmax chain).
// Unnormalized partial ctx^T + (m,l) -> workspace; combine_k merges.
__global__ __launch_bounds__(256, 4) void attn_k(const unsigned short* __restrict__ q,
                                                 const unsigned short* __restrict__ k,
                                                 const unsigned short* __restrict__ vt,
                                                 const float* __restrict__ sw,
                                                 float* __restrict__ part,   // [2][512][64][64] (d,q)
                                                 float* __restrict__ ml) {   // [2][512][64][2]
    __shared__ unsigned short lP[4][640];            // per wave: 16 q-rows x 40 (pad)
    const int t = threadIdx.x, wave = t >> 6, lane = t & 63, c = lane & 15, g = lane >> 4;
    const int blk = blockIdx.x, part_id = blockIdx.y;
    const int qt = blk & 15, bh = blk >> 4, b_ = bh >> 4;
    const int qr = qt * 64 + wave * 16;

    // Q as B-operand: lane holds Q[q=c][hd = g*8..+7] and [32+g*8..]
    const unsigned short* qbase = q + ((size_t)bh * 1024 + qr) * 64;
    s16x8 qf0 = *(const s16x8*)(qbase + (size_t)c * 64 + g * 8);
    s16x8 qf1 = *(const s16x8*)(qbase + (size_t)c * 64 + 32 + g * 8);

    const int kv_base = part_id * 512;
    const unsigned short* kb0 = k + ((size_t)bh * 1024 + kv_base) * 64;
    const unsigned short* vb0 = vt + (size_t)bh * 64 * 1024 + kv_base;
    const float* swrow = sw + ((size_t)b_ * 1024 + qr + c) * 1024 + kv_base;
    unsigned short* wp = lP[wave];

    const float SC  = 0.125f * 1.4426950408889634f;  // (1/sqrt(64)) * log2(e)
    const float L2E = 1.4426950408889634f;

    float mr = -1e30f, lr = 0.0f;    // state for q-row c (replicated over g)
    f32x4 acc[4];                    // acc[nf][r] = ctx^T[d = nf*16+4g+r][q = c]
#pragma unroll
    for (int nf = 0; nf < 4; nf++) acc[nf] = {0.f, 0.f, 0.f, 0.f};

    // prologue: K-fragments + sw for iter 0
    s16x8 kc0 = *(const s16x8*)(kb0 + c * 64 + g * 8);
    s16x8 kc1 = *(const s16x8*)(kb0 + c * 64 + 32 + g * 8);
    s16x8 kc2 = *(const s16x8*)(kb0 + (16 + c) * 64 + g * 8);
    s16x8 kc3 = *(const s16x8*)(kb0 + (16 + c) * 64 + 32 + g * 8);
    float4 swa = *(const float4*)(swrow + 4 * g);
    float4 swb = *(const float4*)(swrow + 16 + 4 * g);

    for (int it = 0; it < 16; ++it) {
        const int kv0 = it * 32;
        const int kvn = ((it + 1) & 15) * 32;        // wraps on last iter (discarded)
        // V for current iter (consumed late -> latency hidden by QK+softmax)
        s16x8 vf[4];
#pragma unroll
        for (int nf = 0; nf < 4; nf++)
            vf[nf] = *(const s16x8*)(vb0 + (size_t)(nf * 16 + c) * 1024 + kv0 + g * 8);
        // prefetch next iter K + sw
        const unsigned short* kbn = kb0 + (size_t)kvn * 64;
        s16x8 kn0 = *(const s16x8*)(kbn + c * 64 + g * 8);
        s16x8 kn1 = *(const s16x8*)(kbn + c * 64 + 32 + g * 8);
        s16x8 kn2 = *(const s16x8*)(kbn + (16 + c) * 64 + g * 8);
        s16x8 kn3 = *(const s16x8*)(kbn + (16 + c) * 64 + 32 + g * 8);
        float4 swna = *(const float4*)(swrow + kvn + 4 * g);
        float4 swnb = *(const float4*)(swrow + kvn + 16 + 4 * g);

        // S^T: lane (c,g): s0[r] = S[k=kv0+4g+r][q=c], s1[r] = +16
        f32x4 s0 = {0.f, 0.f, 0.f, 0.f}, s1 = {0.f, 0.f, 0.f, 0.f};
        s0 = mfma16(kc0, qf0, s0); s0 = mfma16(kc1, qf1, s0);
        s1 = mfma16(kc2, qf0, s1); s1 = mfma16(kc3, qf1, s1);

        float z0[4], z1[4];
#pragma unroll
        for (int r = 0; r < 4; r++) {
            z0[r] = s0[r] * SC + (&swa.x)[r] * L2E;
            z1[r] = s1[r] * SC + (&swb.x)[r] * L2E;
        }
        float tm = fmaxf(fmaxf(fmaxf(z0[0], z0[1]), fmaxf(z0[2], z0[3])),
                         fmaxf(fmaxf(z1[0], z1[1]), fmaxf(z1[2], z1[3])));
        tm = fmaxf(tm, __shfl_xor(tm, 16, 64));
        tm = fmaxf(tm, __shfl_xor(tm, 32, 64));

        bool grow = (tm > mr);
        float mn = grow ? tm : mr;
        float p0[4], p1[4];
#pragma unroll
        for (int r = 0; r < 4; r++) {
            p0[r] = __builtin_amdgcn_exp2f(z0[r] - mn);
            p1[r] = __builtin_amdgcn_exp2f(z1[r] - mn);
        }
        float rs = (p0[0] + p0[1]) + (p0[2] + p0[3]) + (p1[0] + p1[1]) + (p1[2] + p1[3]);
        rs += __shfl_xor(rs, 16, 64);
        rs += __shfl_xor(rs, 32, 64);

        if (__any((int)grow)) {
            float f = __builtin_amdgcn_exp2f(mr - mn);   // lane-local!
            mr = mn;
            lr = lr * f + rs;
#pragma unroll
            for (int nf = 0; nf < 4; nf++)
#pragma unroll
                for (int r = 0; r < 4; r++) acc[nf][r] *= f;
        } else {
            lr += rs;
        }

        // P -> LDS transpose: lane owns (q=c, k=4g..4g+3) and (q=c, k=16+4g..)
        u16x4 w0, w1;
#pragma unroll
        for (int r = 0; r < 4; r++) { w0[r] = f2bf(p0[r]); w1[r] = f2bf(p1[r]); }
        *(u16x4*)(wp + c * 40 + 4 * g) = w0;
        *(u16x4*)(wp + c * 40 + 16 + 4 * g) = w1;
        // P^T B-fragment: lane holds P[q=c][k = g*8 .. g*8+7]
        s16x8 ap = *(const s16x8*)((const char*)wp + c * 80 + g * 16);
        // ctx^T += V^T . P^T
#pragma unroll
        for (int nf = 0; nf < 4; nf++)
            acc[nf] = mfma16(vf[nf], ap, acc[nf]);

        kc0 = kn0; kc1 = kn1; kc2 = kn2; kc3 = kn3; swa = swna; swb = swnb;
    }

    // store unnormalized partial ctx^T tile [d=0..63][q_local=0..63] + (m,l)
    float* ptile = part + ((size_t)part_id * 512 + blk) * 4096;
#pragma unroll
    for (int nf = 0; nf < 4; nf++)
#pragma unroll
        for (int r = 0; r < 4; r++)
            ptile[(nf * 16 + 4 * g + r) * 64 + wave * 16 + c] = acc[nf][r];
    if (g == 0) {
        size_t mb = ((size_t)part_id * 512 + blk) * 128 + (size_t)(wave * 16 + c) * 2;
        ml[mb] = mr; ml[mb + 1] = lr;
    }
}

// ------------------------------- combine ------------------------------------
// block = bh*16+qt: merge 2 partials (exp2-domain m,l), write ctx bf16 [B,L,D].
__global__ __launch_bounds__(256) void combine_k(const float* __restrict__ part,
                                                 const float* __restrict__ ml,
                                                 unsigned short* __restrict__ ctx) {
    __shared__ float t0[64][68], t1[64][68];
    __shared__ float wq[64][2];
    const int t = threadIdx.x;
    const int blk = blockIdx.x;
    const int bh = blk >> 4, qt = blk & 15, b_ = bh >> 4, h = bh & 15;
    const float* p0 = part + (size_t)blk * 4096;
    const float* p1 = p0 + (size_t)512 * 4096;
#pragma unroll
    for (int j = 0; j < 4; j++) {
        int flat = j * 1024 + t * 4;
        int d = flat >> 6, q4 = flat & 63;
        float4 v0 = *(const float4*)(p0 + flat);
        float4 v1 = *(const float4*)(p1 + flat);
        *(float4*)&t0[d][q4] = v0;
        *(float4*)&t1[d][q4] = v1;
    }
    if (t < 64) {
        const float* mlp = ml + (size_t)blk * 128;
        float m0 = mlp[t * 2], l0 = mlp[t * 2 + 1];
        float m1 = mlp[65536 + t * 2], l1 = mlp[65536 + t * 2 + 1];
        float M = fmaxf(m0, m1);
        float w0 = __builtin_amdgcn_exp2f(m0 - M);
        float w1 = __builtin_amdgcn_exp2f(m1 - M);
        float inv = 1.0f / (w0 * l0 + w1 * l1);
        wq[t][0] = w0 * inv; wq[t][1] = w1 * inv;
    }
    __syncthreads();
    const int q = t >> 2, db = (t & 3) * 16;
    const float w0 = wq[q][0], w1 = wq[q][1];
    u16x8 o0, o1;
#pragma unroll
    for (int i = 0; i < 8; i++) o0[i] = f2bf(t0[db + i][q] * w0 + t1[db + i][q] * w1);
#pragma unroll
    for (int i = 0; i < 8; i++) o1[i] = f2bf(t0[db + 8 + i][q] * w0 + t1[db + 8 + i][q] * w1);
    unsigned short* dst = ctx + ((size_t)(b_ << 10) + qt * 64 + q) * 1024 + (h << 6) + db;
    *(u16x8*)dst = o0;
    *(u16x8*)(dst + 8) = o1;
}

// ------------------------------- launch ------------------------------------
extern "C" void kernel_launch(void* const* d_in, const int* in_sizes, int n_in,
                              void* d_out, int out_size, void* d_ws, size_t ws_size,
                              hipStream_t stream) {
    const float* x    = (const float*)d_in[0];
    const float* sb   = (const float*)d_in[1];
    const float* Wqkv = (const float*)d_in[2];
    const float* bqkv = (const float*)d_in[3];
    const float* Ws   = (const float*)d_in[4];
    const float* bs   = (const float*)d_in[5];
    const float* Wo   = (const float*)d_in[6];
    const float* bo   = (const float*)d_in[7];
    float* out = (float*)d_out;

    char* ws = (char*)d_ws;
    float*          partial = (float*)(ws);                      // 16MB (reuses early region)
    unsigned short* xb    = (unsigned short*)(ws);
    unsigned short* sbb   = (unsigned short*)(ws + ((size_t)4 << 20));
    unsigned short* wqkvt = (unsigned short*)(ws + ((size_t)8 << 20));
    unsigned short* wst   = (unsigned short*)(ws + ((size_t)14 << 20));
    unsigned short* wot   = (unsigned short*)(ws + ((size_t)16 << 20));
    unsigned short* qb    = (unsigned short*)(ws + ((size_t)18 << 20));
    unsigned short* kb    = (unsigned short*)(ws + ((size_t)22 << 20));
    unsigned short* vtb   = (unsigned short*)(ws + ((size_t)26 << 20));
    float*          swf   = (float*)        (ws + ((size_t)30 << 20));
    unsigned short* ctxb  = (unsigned short*)(ws + ((size_t)38 << 20));
    float*          mlb   = (float*)        (ws + ((size_t)42 << 20));

    cvt_bf16_k<<<dim3(1024), dim3(256), 0, stream>>>(x, xb);
    cvt_bf16_k<<<dim3(1024), dim3(256), 0, stream>>>(sb, sbb);
    transpose_w_k<<<dim3(48, 16), dim3(256), 0, stream>>>(Wqkv, wqkvt, 3072);
    transpose_w_k<<<dim3(16, 16), dim3(256), 0, stream>>>(Ws, wst, 1024);
    transpose_w_k<<<dim3(16, 16), dim3(256), 0, stream>>>(Wo, wot, 1024);
    gemm_k<0, 64, 128><<<dim3(24, 32), dim3(256), 0, stream>>>(xb, wqkvt, bqkv, qb, kb, vtb, (float*)nullptr);
    gemm_k<1, 128, 64><<<dim3(16, 16), dim3(256), 0, stream>>>(sbb, wst, bs,
                                                               (unsigned short*)nullptr, (unsigned short*)nullptr,
                                                               (unsigned short*)nullptr, swf);
    attn_k<<<dim3(512, 2), dim3(256), 0, stream>>>(qb, kb, vtb, swf, partial, mlb);
    combine_k<<<dim3(512), dim3(256), 0, stream>>>(partial, mlb, ctxb);
    gemm_k<1, 128, 64><<<dim3(16, 16), dim3(256), 0, stream>>>(ctxb, wot, bo,
                                                               (unsigned short*)nullptr, (unsigned short*)nullptr,
                                                               (unsigned short*)nullptr, out);
}

// Round 4
// 115.530 us; speedup vs baseline: 1.4466x; 1.4224x over previous
//
#include <hip/hip_runtime.h>
#include <stdint.h>
#include <stddef.h>

// ---------------------------------------------------------------------------
// StructureAwareAttention  (B=2, L=1024, D=1024, H=16, HD=64)
//   qkv = x@Wqkv + bqkv            -> q,k [B,H,L,64] bf16, v^T [B,H,64,L] bf16
//   sw  = sb@Ws + bs               -> f32 [B,L,L]
//   attn: flash, swapped QK^T + swapped PV (lane-local state), K/V LDS-staged
//         (double-buffered, XOR-swizzled both sides), KVBLK=64
//   out = ctx@Wo + bo              -> f32 [B,L,D]
// Workspace:
//   0: xb 4MB | 4MB: sbb 4MB | 8MB: Wqkv^T 6MB | 14MB: Ws^T 2MB | 16MB: Wo^T 2MB
//   18MB: q 4MB | 22MB: k 4MB | 26MB: v^T 4MB | 30MB: sw(f32) 8MB | 38MB: ctx 4MB
// ---------------------------------------------------------------------------

typedef float f32x4 __attribute__((ext_vector_type(4)));
typedef short s16x8 __attribute__((ext_vector_type(8)));
typedef unsigned short u16x8 __attribute__((ext_vector_type(8)));
typedef unsigned short u16x4 __attribute__((ext_vector_type(4)));

__device__ inline unsigned short f2bf(float f) {          // RNE f32 -> bf16
    unsigned u = __builtin_bit_cast(unsigned, f);
    u += 0x7fffu + ((u >> 16) & 1u);
    return (unsigned short)(u >> 16);
}

__device__ inline f32x4 mfma16(s16x8 a, s16x8 b, f32x4 c) {
    return __builtin_amdgcn_mfma_f32_16x16x32_bf16(a, b, c, 0, 0, 0);
}

__device__ inline void gld_lds16(const void* g, const void* lds_base) {
    __builtin_amdgcn_global_load_lds(
        (const __attribute__((address_space(1))) void*)(uintptr_t)g,
        (__attribute__((address_space(3))) void*)(unsigned)(uintptr_t)lds_base,
        16, 0, 0);
}

// -------------------------------- convert ----------------------------------
__global__ void cvt_bf16_k(const float* __restrict__ src, unsigned short* __restrict__ dst) {
    int i = blockIdx.x * 256 + threadIdx.x;
    const float4* s4 = (const float4*)src;
    float4 a = s4[2 * i], b = s4[2 * i + 1];
    u16x8 o;
    o[0] = f2bf(a.x); o[1] = f2bf(a.y); o[2] = f2bf(a.z); o[3] = f2bf(a.w);
    o[4] = f2bf(b.x); o[5] = f2bf(b.y); o[6] = f2bf(b.z); o[7] = f2bf(b.w);
    *(u16x8*)(dst + (size_t)i * 8) = o;
}

// ---------------------- weight transpose: W[K][N] -> Wt[N][K] bf16 ----------
__global__ __launch_bounds__(256) void transpose_w_k(const float* __restrict__ W,
                                                     unsigned short* __restrict__ Wt, int N) {
    __shared__ float tile[64][65];
    const int t = threadIdx.x;
    const int n0 = blockIdx.x * 64, k0 = blockIdx.y * 64;
    const int lr = t >> 4, lc = (t & 15) * 4;
#pragma unroll
    for (int rr = 0; rr < 4; rr++) {
        int r = lr + rr * 16;
        float4 v = *(const float4*)(W + (size_t)(k0 + r) * N + n0 + lc);
        tile[r][lc] = v.x; tile[r][lc + 1] = v.y; tile[r][lc + 2] = v.z; tile[r][lc + 3] = v.w;
    }
    __syncthreads();
    const int wn = t >> 3, wk = (t & 7) * 8;
#pragma unroll
    for (int rr = 0; rr < 2; rr++) {
        int n = wn + rr * 32;
        u16x8 o;
#pragma unroll
        for (int j = 0; j < 8; j++) o[j] = f2bf(tile[wk + j][n]);
        *(u16x8*)(Wt + (size_t)(n0 + n) * 1024 + k0 + wk) = o;
    }
}

// ------------------------------- GEMM --------------------------------------
// C[M,N] = A[M,1024] @ Bt[N,1024]^T + bias.  BM x BN tile, BK=32, 4 waves.
template <int EPI, int BM, int BN>
__global__ __launch_bounds__(256) void gemm_k(const unsigned short* __restrict__ A,
                                              const unsigned short* __restrict__ Bt,
                                              const float* __restrict__ bias,
                                              unsigned short* __restrict__ q,
                                              unsigned short* __restrict__ kk_,
                                              unsigned short* __restrict__ vt,
                                              float* __restrict__ outf) {
    __shared__ unsigned short lA[BM * 32], lB[BN * 32];
    const int t = threadIdx.x;
    const int wave = t >> 6, lane = t & 63, c = lane & 15, g = lane >> 4;
    const int bn0 = blockIdx.x * BN, bm0 = blockIdx.y * BM;
    constexpr int MI = (BN == 64) ? 2 : 4;
    constexpr int NI = (BN == 64) ? 4 : (BM == 64 ? 2 : 4);
    int wr, wc;
    if (BM == 64)      { wr = 0;                wc = wave * 32; }
    else if (BN == 64) { wr = wave * 32;        wc = 0; }
    else               { wr = (wave >> 1) * 64; wc = (wave & 1) * 64; }
    const int row = t >> 2, p = t & 3;
    const int gg = p ^ ((row >> 1) & 3);
    const size_t aoff = (size_t)(bm0 + row) * 1024 + gg * 8;
    const size_t boff = (size_t)(bn0 + row) * 1024 + gg * 8;
    char* lAb = (char*)lA; char* lBb = (char*)lB;

    f32x4 acc[MI][NI];
#pragma unroll
    for (int i = 0; i < MI; i++)
#pragma unroll
        for (int j = 0; j < NI; j++) acc[i][j] = {0.f, 0.f, 0.f, 0.f};

    for (int kt = 0; kt < 1024; kt += 32) {
        __syncthreads();
#pragma unroll
        for (int h = 0; h < BM / 64; h++)
            gld_lds16(A + aoff + (size_t)h * 64 * 1024 + kt, lAb + h * 4096 + wave * 1024);
#pragma unroll
        for (int h = 0; h < BN / 64; h++)
            gld_lds16(Bt + boff + (size_t)h * 64 * 1024 + kt, lBb + h * 4096 + wave * 1024);
        __syncthreads();
        s16x8 af[MI], bfr[NI];
#pragma unroll
        for (int i = 0; i < MI; i++) {
            int r_ = wr + i * 16 + c;
            af[i] = *(const s16x8*)(lAb + r_ * 64 + ((g ^ ((r_ >> 1) & 3)) << 4));
        }
#pragma unroll
        for (int j = 0; j < NI; j++) {
            int r_ = wc + j * 16 + c;
            bfr[j] = *(const s16x8*)(lBb + r_ * 64 + ((g ^ ((r_ >> 1) & 3)) << 4));
        }
#pragma unroll
        for (int i = 0; i < MI; i++)
#pragma unroll
            for (int j = 0; j < NI; j++)
                acc[i][j] = mfma16(af[i], bfr[j], acc[i][j]);
    }

#pragma unroll
    for (int i = 0; i < MI; i++) {
#pragma unroll
        for (int j = 0; j < NI; j++) {
            const int n = bn0 + wc + j * 16 + c;
            const float bv = bias[n];
#pragma unroll
            for (int r = 0; r < 4; r++) {
                const int m = bm0 + wr + i * 16 + g * 4 + r;
                float v = acc[i][j][r] + bv;
                if (EPI == 0) {
                    const int sel = n >> 10, h = (n >> 6) & 15, d = n & 63;
                    const int b_ = m >> 10, l_ = m & 1023;
                    const size_t bh = (size_t)((b_ << 4) + h);
                    unsigned short hv = f2bf(v);
                    if (sel == 0)      q[(bh * 1024 + l_) * 64 + d] = hv;
                    else if (sel == 1) kk_[(bh * 1024 + l_) * 64 + d] = hv;
                    else               vt[(bh * 64 + d) * 1024 + l_] = hv;
                } else {
                    outf[(size_t)m * 1024 + n] = v;
                }
            }
        }
    }
}

// ------------------------------ attention ----------------------------------
// grid 512: block = (bh, 64 q-rows), wave = 16 q-rows, full KV sweep.
// KVBLK=64: K[64x64] + V^T[64x64] staged in LDS (double-buffered) via
// global_load_lds with pre-swizzled SOURCE (chunk ^= row&7); ds_read_b128 with
// matching XOR -> ~2-way conflicts. Swapped QK^T (S^T=mfma(K,Q)) and swapped
// PV (ctx^T=mfma(V^T,P^T)): softmax state m,l and rescale fully lane-local.
// Epilogue: normalize, transpose ctx^T->ctx through padded LDS scratch.
__global__ __launch_bounds__(256, 2) void attn_k(const unsigned short* __restrict__ q,
                                                 const unsigned short* __restrict__ k,
                                                 const unsigned short* __restrict__ vt,
                                                 const float* __restrict__ sw,
                                                 unsigned short* __restrict__ ctx) {
    __shared__ unsigned short kbuf[2][4096];         // [64 kv][64 hd] swizzled, 8KB/buf
    __shared__ unsigned short vbuf[2][4096];         // [64 d][64 kv] swizzled, 8KB/buf
    __shared__ unsigned short lP[4][640];            // per wave: 16 q-rows x 40 (pad)
    const int t = threadIdx.x, wave = t >> 6, lane = t & 63, c = lane & 15, g = lane >> 4;
    const int blk = blockIdx.x;
    const int qt = blk & 15, bh = blk >> 4, b_ = bh >> 4, h = bh & 15;
    const int qr = qt * 64 + wave * 16;

    // Q as B-operand: lane holds Q[q=c][hd = g*8..+7] and [32+g*8..]
    const unsigned short* qbase = q + ((size_t)bh * 1024 + qr) * 64;
    s16x8 qf0 = *(const s16x8*)(qbase + (size_t)c * 64 + g * 8);
    s16x8 qf1 = *(const s16x8*)(qbase + (size_t)c * 64 + 32 + g * 8);

    const unsigned short* kg = k + (size_t)bh * 65536;     // [1024][64]
    const unsigned short* vg = vt + (size_t)bh * 65536;    // [64][1024]
    const float* swrow = sw + ((size_t)b_ * 1024 + qr + c) * 1024;

    // staging: 512 16B-slots per tile; wave stages slots [wave*128, wave*128+128)
    const int s0 = wave * 128 + lane, s1 = s0 + 64;
    const int r0 = s0 >> 3, ch0 = (s0 & 7) ^ (r0 & 7);
    const int r1 = s1 >> 3, ch1 = (s1 & 7) ^ (r1 & 7);

    const float SC  = 0.125f * 1.4426950408889634f;  // (1/sqrt(64)) * log2(e)
    const float L2E = 1.4426950408889634f;

    float mr = -1e30f, lr = 0.0f;    // state for q-row c (replicated over g)
    f32x4 acc[4];                    // acc[nf][r] = ctx^T[d = nf*16+4g+r][q = c]
#pragma unroll
    for (int nf = 0; nf < 4; nf++) acc[nf] = {0.f, 0.f, 0.f, 0.f};
    unsigned short* wp = lP[wave];
    const int swz = (c & 7);

#define STAGE(buf, kv0)                                                                     \
    do {                                                                                    \
        gld_lds16(kg + (size_t)((kv0) + r0) * 64 + ch0 * 8, (char*)kbuf[buf] + wave * 2048);            \
        gld_lds16(kg + (size_t)((kv0) + r1) * 64 + ch1 * 8, (char*)kbuf[buf] + wave * 2048 + 1024);     \
        gld_lds16(vg + (size_t)r0 * 1024 + (kv0) + ch0 * 8, (char*)vbuf[buf] + wave * 2048);            \
        gld_lds16(vg + (size_t)r1 * 1024 + (kv0) + ch1 * 8, (char*)vbuf[buf] + wave * 2048 + 1024);     \
    } while (0)

    STAGE(0, 0);
    __syncthreads();

    int cur = 0;
    for (int it = 0; it < 16; ++it) {
        const int kv0 = it * 64;
        if (it < 15) STAGE(cur ^ 1, kv0 + 64);
        float4 sws[4];
#pragma unroll
        for (int j = 0; j < 4; j++) sws[j] = *(const float4*)(swrow + kv0 + j * 16 + 4 * g);

        const char* kB = (const char*)kbuf[cur];
        const char* vB = (const char*)vbuf[cur];
#pragma unroll
        for (int ks2 = 0; ks2 < 2; ++ks2) {
            s16x8 kc0 = *(const s16x8*)(kB + ((ks2 * 32 + c) << 7) + (((0 + g) ^ swz) << 4));
            s16x8 kc1 = *(const s16x8*)(kB + ((ks2 * 32 + c) << 7) + (((4 + g) ^ swz) << 4));
            s16x8 kc2 = *(const s16x8*)(kB + ((ks2 * 32 + 16 + c) << 7) + (((0 + g) ^ swz) << 4));
            s16x8 kc3 = *(const s16x8*)(kB + ((ks2 * 32 + 16 + c) << 7) + (((4 + g) ^ swz) << 4));

            f32x4 ss0 = {0.f, 0.f, 0.f, 0.f}, ss1 = {0.f, 0.f, 0.f, 0.f};
            ss0 = mfma16(kc0, qf0, ss0); ss0 = mfma16(kc1, qf1, ss0);
            ss1 = mfma16(kc2, qf0, ss1); ss1 = mfma16(kc3, qf1, ss1);

            float4 swa = sws[2 * ks2], swb = sws[2 * ks2 + 1];
            float z0[4], z1[4];
#pragma unroll
            for (int r = 0; r < 4; r++) {
                z0[r] = ss0[r] * SC + (&swa.x)[r] * L2E;
                z1[r] = ss1[r] * SC + (&swb.x)[r] * L2E;
            }
            float tm = fmaxf(fmaxf(fmaxf(z0[0], z0[1]), fmaxf(z0[2], z0[3])),
                             fmaxf(fmaxf(z1[0], z1[1]), fmaxf(z1[2], z1[3])));
            tm = fmaxf(tm, __shfl_xor(tm, 16, 64));
            tm = fmaxf(tm, __shfl_xor(tm, 32, 64));

            bool grow = (tm > mr);
            float mn = grow ? tm : mr;
            float p0[4], p1[4];
#pragma unroll
            for (int r = 0; r < 4; r++) {
                p0[r] = __builtin_amdgcn_exp2f(z0[r] - mn);
                p1[r] = __builtin_amdgcn_exp2f(z1[r] - mn);
            }
            float rs = (p0[0] + p0[1]) + (p0[2] + p0[3]) + (p1[0] + p1[1]) + (p1[2] + p1[3]);
            rs += __shfl_xor(rs, 16, 64);
            rs += __shfl_xor(rs, 32, 64);

            if (__any((int)grow)) {
                float f = __builtin_amdgcn_exp2f(mr - mn);   // lane-local
                mr = mn;
                lr = lr * f + rs;
#pragma unroll
                for (int nf = 0; nf < 4; nf++)
#pragma unroll
                    for (int r = 0; r < 4; r++) acc[nf][r] *= f;
            } else {
                lr += rs;
            }

            // P -> LDS transpose: lane owns (q=c, k=4g..4g+3) and (q=c, k=16+4g..)
            u16x4 w0, w1;
#pragma unroll
            for (int r = 0; r < 4; r++) { w0[r] = f2bf(p0[r]); w1[r] = f2bf(p1[r]); }
            *(u16x4*)(wp + c * 40 + 4 * g) = w0;
            *(u16x4*)(wp + c * 40 + 16 + 4 * g) = w1;
            // P^T B-fragment: lane holds P[q=c][k = g*8 .. g*8+7]
            s16x8 ap = *(const s16x8*)((const char*)wp + c * 80 + g * 16);

#pragma unroll
            for (int nf = 0; nf < 4; nf++) {
                s16x8 vf = *(const s16x8*)(vB + ((nf * 16 + c) << 7) + ((((ks2 << 2) + g) ^ swz) << 4));
                acc[nf] = mfma16(vf, ap, acc[nf]);       // ctx^T += V^T . P^T
            }
        }
        __syncthreads();
        cur ^= 1;
    }
#undef STAGE

    // epilogue: normalize (lane-local), transpose ctx^T -> ctx via LDS scratch
    float inv = 1.0f / lr;
#pragma unroll
    for (int nf = 0; nf < 4; nf++)
#pragma unroll
        for (int r = 0; r < 4; r++) acc[nf][r] *= inv;

    __syncthreads();                                  // staging bufs now dead
    float* scr = (wave < 2) ? ((float*)kbuf + wave * 1088)
                            : ((float*)vbuf + (wave - 2) * 1088);   // 64 x 17 f32
#pragma unroll
    for (int nf = 0; nf < 4; nf++)
#pragma unroll
        for (int r = 0; r < 4; r++)
            scr[(nf * 16 + 4 * g + r) * 17 + c] = acc[nf][r];
    __syncthreads();
    // lane (c,g): output row q=c, d = g*16 .. g*16+15
    u16x8 o0, o1;
#pragma unroll
    for (int j = 0; j < 8; j++) o0[j] = f2bf(scr[(g * 16 + j) * 17 + c]);
#pragma unroll
    for (int j = 0; j < 8; j++) o1[j] = f2bf(scr[(g * 16 + 8 + j) * 17 + c]);
    unsigned short* dst = ctx + ((size_t)(b_ << 10) + qr + c) * 1024 + (h << 6) + g * 16;
    *(u16x8*)dst = o0;
    *(u16x8*)(dst + 8) = o1;
}

// ------------------------------- launch ------------------------------------
extern "C" void kernel_launch(void* const* d_in, const int* in_sizes, int n_in,
                              void* d_out, int out_size, void* d_ws, size_t ws_size,
                              hipStream_t stream) {
    const float* x    = (const float*)d_in[0];
    const float* sb   = (const float*)d_in[1];
    const float* Wqkv = (const float*)d_in[2];
    const float* bqkv = (const float*)d_in[3];
    const float* Ws   = (const float*)d_in[4];
    const float* bs   = (const float*)d_in[5];
    const float* Wo   = (const float*)d_in[6];
    const float* bo   = (const float*)d_in[7];
    float* out = (float*)d_out;

    char* ws = (char*)d_ws;
    unsigned short* xb    = (unsigned short*)(ws);
    unsigned short* sbb   = (unsigned short*)(ws + ((size_t)4 << 20));
    unsigned short* wqkvt = (unsigned short*)(ws + ((size_t)8 << 20));
    unsigned short* wst   = (unsigned short*)(ws + ((size_t)14 << 20));
    unsigned short* wot   = (unsigned short*)(ws + ((size_t)16 << 20));
    unsigned short* qb    = (unsigned short*)(ws + ((size_t)18 << 20));
    unsigned short* kb    = (unsigned short*)(ws + ((size_t)22 << 20));
    unsigned short* vtb   = (unsigned short*)(ws + ((size_t)26 << 20));
    float*          swf   = (float*)        (ws + ((size_t)30 << 20));
    unsigned short* ctxb  = (unsigned short*)(ws + ((size_t)38 << 20));

    cvt_bf16_k<<<dim3(1024), dim3(256), 0, stream>>>(x, xb);
    cvt_bf16_k<<<dim3(1024), dim3(256), 0, stream>>>(sb, sbb);
    transpose_w_k<<<dim3(48, 16), dim3(256), 0, stream>>>(Wqkv, wqkvt, 3072);
    transpose_w_k<<<dim3(16, 16), dim3(256), 0, stream>>>(Ws, wst, 1024);
    transpose_w_k<<<dim3(16, 16), dim3(256), 0, stream>>>(Wo, wot, 1024);
    gemm_k<0, 64, 128><<<dim3(24, 32), dim3(256), 0, stream>>>(xb, wqkvt, bqkv, qb, kb, vtb, (float*)nullptr);
    gemm_k<1, 128, 64><<<dim3(16, 16), dim3(256), 0, stream>>>(sbb, wst, bs,
                                                               (unsigned short*)nullptr, (unsigned short*)nullptr,
                                                               (unsigned short*)nullptr, swf);
    attn_k<<<dim3(512), dim3(256), 0, stream>>>(qb, kb, vtb, swf, ctxb);
    gemm_k<1, 128, 64><<<dim3(16, 16), dim3(256), 0, stream>>>(ctxb, wot, bo,
                                                               (unsigned short*)nullptr, (unsigned short*)nullptr,
                                                               (unsigned short*)nullptr, out);
}

// Round 5
// 92.375 us; speedup vs baseline: 1.8092x; 1.2507x over previous
//
#include <hip/hip_runtime.h>
#include <stdint.h>
#include <stddef.h>

// ---------------------------------------------------------------------------
// StructureAwareAttention  (B=2, L=1024, D=1024, H=16, HD=64)
//   prep: cvt x,sb -> bf16; transpose Wqkv/Ws/Wo -> [N][K] bf16   (1 kernel)
//   qkv = x@Wqkv + bqkv            -> q,k [B,H,L,64] bf16, v^T [B,H,64,L] bf16
//   sw  = sb@Ws + bs               -> f32 [B,L,L]
//   attn: flash, swapped QK^T + swapped PV (lane-local state), K/V LDS-staged
//         (double-buffered, XOR-swizzled both sides), KVBLK=64, defer-max
//   out = ctx@Wo + bo              -> f32 [B,L,D]
// GEMMs: 64x128 tile, BK=64, 2-phase double-buffered LDS (1 barrier/K-step).
// Workspace:
//   0: xb 4MB | 4MB: sbb 4MB | 8MB: Wqkv^T 6MB | 14MB: Ws^T 2MB | 16MB: Wo^T 2MB
//   18MB: q 4MB | 22MB: k 4MB | 26MB: v^T 4MB | 30MB: sw(f32) 8MB | 38MB: ctx 4MB
// ---------------------------------------------------------------------------

typedef float f32x4 __attribute__((ext_vector_type(4)));
typedef short s16x8 __attribute__((ext_vector_type(8)));
typedef unsigned short u16x8 __attribute__((ext_vector_type(8)));
typedef unsigned short u16x4 __attribute__((ext_vector_type(4)));

__device__ inline unsigned short f2bf(float f) {          // RNE f32 -> bf16
    unsigned u = __builtin_bit_cast(unsigned, f);
    u += 0x7fffu + ((u >> 16) & 1u);
    return (unsigned short)(u >> 16);
}

__device__ inline f32x4 mfma16(s16x8 a, s16x8 b, f32x4 c) {
    return __builtin_amdgcn_mfma_f32_16x16x32_bf16(a, b, c, 0, 0, 0);
}

__device__ inline void gld_lds16(const void* g, const void* lds_base) {
    __builtin_amdgcn_global_load_lds(
        (const __attribute__((address_space(1))) void*)(uintptr_t)g,
        (__attribute__((address_space(3))) void*)(unsigned)(uintptr_t)lds_base,
        16, 0, 0);
}

// ------------------------------ prep ---------------------------------------
// blocks [0,1024): cvt x | [1024,2048): cvt sb | [2048,2816): Wqkv^T
// [2816,3072): Ws^T | [3072,3328): Wo^T
__global__ __launch_bounds__(256) void prep_k(const float* __restrict__ x,
                                              const float* __restrict__ sb,
                                              const float* __restrict__ Wqkv,
                                              const float* __restrict__ Ws,
                                              const float* __restrict__ Wo,
                                              unsigned short* __restrict__ xb,
                                              unsigned short* __restrict__ sbb,
                                              unsigned short* __restrict__ wqkvt,
                                              unsigned short* __restrict__ wst,
                                              unsigned short* __restrict__ wot) {
    __shared__ float tile[64][65];
    const int blk = blockIdx.x, t = threadIdx.x;
    if (blk < 2048) {                                   // bf16 convert, 8 elem/thread
        const float* src = (blk < 1024) ? x : sb;
        unsigned short* dst = (blk < 1024) ? xb : sbb;
        int i = (blk & 1023) * 256 + t;
        const float4* s4 = (const float4*)src;
        float4 a = s4[2 * i], b = s4[2 * i + 1];
        u16x8 o;
        o[0] = f2bf(a.x); o[1] = f2bf(a.y); o[2] = f2bf(a.z); o[3] = f2bf(a.w);
        o[4] = f2bf(b.x); o[5] = f2bf(b.y); o[6] = f2bf(b.z); o[7] = f2bf(b.w);
        *(u16x8*)(dst + (size_t)i * 8) = o;
        return;
    }
    // weight transpose W[K=1024][N] -> Wt[N][1024] bf16, 64x64 tiles
    int tt = blk - 2048;
    const float* W; unsigned short* Wt; int N, n0, k0;
    if (tt < 768)       { W = Wqkv; Wt = wqkvt; N = 3072; n0 = (tt % 48) * 64; k0 = (tt / 48) * 64; }
    else if (tt < 1024) { tt -= 768;  W = Ws; Wt = wst; N = 1024; n0 = (tt & 15) * 64; k0 = (tt >> 4) * 64; }
    else                { tt -= 1024; W = Wo; Wt = wot; N = 1024; n0 = (tt & 15) * 64; k0 = (tt >> 4) * 64; }
    const int lr = t >> 4, lc = (t & 15) * 4;
#pragma unroll
    for (int rr = 0; rr < 4; rr++) {
        int r = lr + rr * 16;
        float4 v = *(const float4*)(W + (size_t)(k0 + r) * N + n0 + lc);
        tile[r][lc] = v.x; tile[r][lc + 1] = v.y; tile[r][lc + 2] = v.z; tile[r][lc + 3] = v.w;
    }
    __syncthreads();
    const int wn = t >> 3, wk = (t & 7) * 8;
#pragma unroll
    for (int rr = 0; rr < 2; rr++) {
        int n = wn + rr * 32;
        u16x8 o;
#pragma unroll
        for (int j = 0; j < 8; j++) o[j] = f2bf(tile[wk + j][n]);
        *(u16x8*)(Wt + (size_t)(n0 + n) * 1024 + k0 + wk) = o;
    }
}

// ------------------------------- GEMM --------------------------------------
// C[M,N] = A[M,1024] @ Bt[N,1024]^T + bias.  64x128 tile, BK=64, 4 waves,
// double-buffered LDS, 1 barrier per K-step (stage next || compute cur).
// Rows are 8 16B-chunks; stage puts logical chunk (p ^ (row&7)) at phys p;
// read XORs back -> conflict-light ds_read_b128.
// EPI 0: scatter bf16 into q/k [B,H,L,64] and v^T [B,H,64,L] (N=3072)
// EPI 1: f32 row-major [M][1024]
template <int EPI>
__global__ __launch_bounds__(256, 3) void gemm_k(const unsigned short* __restrict__ A,
                                                 const unsigned short* __restrict__ Bt,
                                                 const float* __restrict__ bias,
                                                 unsigned short* __restrict__ q,
                                                 unsigned short* __restrict__ kk_,
                                                 unsigned short* __restrict__ vt,
                                                 float* __restrict__ outf) {
    __shared__ unsigned short lA[2][4096];   // [64 m][64 k]
    __shared__ unsigned short lB[2][8192];   // [128 n][64 k]
    const int t = threadIdx.x;
    const int wave = t >> 6, lane = t & 63, c = lane & 15, g = lane >> 4;
    const int bn0 = blockIdx.x * 128, bm0 = blockIdx.y * 64;
    const int wc = wave * 32;

    // staging constants: slot s -> row=s>>3, phys chunk s&7 holds logical (s&7)^(row&7)
    size_t aoff[2], boff[4];
#pragma unroll
    for (int j = 0; j < 2; j++) {
        int s = j * 256 + t, row = s >> 3, ch = (s & 7) ^ (row & 7);
        aoff[j] = (size_t)(bm0 + row) * 1024 + ch * 8;
    }
#pragma unroll
    for (int j = 0; j < 4; j++) {
        int s = j * 256 + t, row = s >> 3, ch = (s & 7) ^ (row & 7);
        boff[j] = (size_t)(bn0 + row) * 1024 + ch * 8;
    }
    char* lAb0 = (char*)lA[0]; char* lBb0 = (char*)lB[0];

#define GSTAGE(buf, kt)                                                                  \
    do {                                                                                 \
        _Pragma("unroll")                                                                \
        for (int j = 0; j < 2; j++)                                                      \
            gld_lds16(A + aoff[j] + (kt), lAb0 + (buf) * 8192 + j * 4096 + wave * 1024); \
        _Pragma("unroll")                                                                \
        for (int j = 0; j < 4; j++)                                                      \
            gld_lds16(Bt + boff[j] + (kt), lBb0 + (buf) * 16384 + j * 4096 + wave * 1024);\
    } while (0)

    f32x4 acc[4][2];
#pragma unroll
    for (int i = 0; i < 4; i++)
#pragma unroll
        for (int j = 0; j < 2; j++) acc[i][j] = {0.f, 0.f, 0.f, 0.f};

    GSTAGE(0, 0);
    for (int ks = 0; ks < 16; ++ks) {
        __syncthreads();                              // drains stage of buf ks&1
        if (ks < 15) GSTAGE((ks + 1) & 1, (ks + 1) * 64);
        const char* aB = lAb0 + (ks & 1) * 8192;
        const char* bB = lBb0 + (ks & 1) * 16384;
#pragma unroll
        for (int kk2 = 0; kk2 < 2; ++kk2) {
            s16x8 af[4], bfr[2];
#pragma unroll
            for (int i = 0; i < 4; i++) {
                int r_ = i * 16 + c;
                af[i] = *(const s16x8*)(aB + r_ * 128 + (((kk2 * 4 + g) ^ (r_ & 7)) << 4));
            }
#pragma unroll
            for (int j = 0; j < 2; j++) {
                int r_ = wc + j * 16 + c;
                bfr[j] = *(const s16x8*)(bB + r_ * 128 + (((kk2 * 4 + g) ^ (r_ & 7)) << 4));
            }
#pragma unroll
            for (int i = 0; i < 4; i++)
#pragma unroll
                for (int j = 0; j < 2; j++)
                    acc[i][j] = mfma16(af[i], bfr[j], acc[i][j]);
        }
    }
#undef GSTAGE

#pragma unroll
    for (int i = 0; i < 4; i++) {
#pragma unroll
        for (int j = 0; j < 2; j++) {
            const int n = bn0 + wc + j * 16 + c;
            const float bv = bias[n];
#pragma unroll
            for (int r = 0; r < 4; r++) {
                const int m = bm0 + i * 16 + g * 4 + r;
                float v = acc[i][j][r] + bv;
                if (EPI == 0) {
                    const int sel = n >> 10, h = (n >> 6) & 15, d = n & 63;
                    const int b_ = m >> 10, l_ = m & 1023;
                    const size_t bh = (size_t)((b_ << 4) + h);
                    unsigned short hv = f2bf(v);
                    if (sel == 0)      q[(bh * 1024 + l_) * 64 + d] = hv;
                    else if (sel == 1) kk_[(bh * 1024 + l_) * 64 + d] = hv;
                    else               vt[(bh * 64 + d) * 1024 + l_] = hv;
                } else {
                    outf[(size_t)m * 1024 + n] = v;
                }
            }
        }
    }
}

// ------------------------------ attention ----------------------------------
// grid 512: block = (bh, 64 q-rows), wave = 16 q-rows, full KV sweep.
// KVBLK=64: K/V^T staged in LDS (double-buffered, swizzled both sides).
// Swapped QK^T + swapped PV: softmax state fully lane-local. Defer-max
// (THR=8 in exp2 domain): skip acc-rescale unless tile max grows past budget.
__global__ __launch_bounds__(256, 2) void attn_k(const unsigned short* __restrict__ q,
                                                 const unsigned short* __restrict__ k,
                                                 const unsigned short* __restrict__ vt,
                                                 const float* __restrict__ sw,
                                                 unsigned short* __restrict__ ctx) {
    __shared__ unsigned short kbuf[2][4096];         // [64 kv][64 hd] swizzled
    __shared__ unsigned short vbuf[2][4096];         // [64 d][64 kv] swizzled
    __shared__ unsigned short lP[4][640];            // per wave: 16 q-rows x 40 (pad)
    const int t = threadIdx.x, wave = t >> 6, lane = t & 63, c = lane & 15, g = lane >> 4;
    const int blk = blockIdx.x;
    const int qt = blk & 15, bh = blk >> 4, b_ = bh >> 4, h = bh & 15;
    const int qr = qt * 64 + wave * 16;

    const unsigned short* qbase = q + ((size_t)bh * 1024 + qr) * 64;
    s16x8 qf0 = *(const s16x8*)(qbase + (size_t)c * 64 + g * 8);
    s16x8 qf1 = *(const s16x8*)(qbase + (size_t)c * 64 + 32 + g * 8);

    const unsigned short* kg = k + (size_t)bh * 65536;     // [1024][64]
    const unsigned short* vg = vt + (size_t)bh * 65536;    // [64][1024]
    const float* swrow = sw + ((size_t)b_ * 1024 + qr + c) * 1024;

    const int s0 = wave * 128 + lane, s1 = s0 + 64;
    const int r0 = s0 >> 3, ch0 = (s0 & 7) ^ (r0 & 7);
    const int r1 = s1 >> 3, ch1 = (s1 & 7) ^ (r1 & 7);

    const float SC  = 0.125f * 1.4426950408889634f;
    const float L2E = 1.4426950408889634f;

    float mr = -1e30f, lr = 0.0f;    // state for q-row c (replicated over g)
    f32x4 acc[4];                    // acc[nf][r] = ctx^T[d = nf*16+4g+r][q = c]
#pragma unroll
    for (int nf = 0; nf < 4; nf++) acc[nf] = {0.f, 0.f, 0.f, 0.f};
    unsigned short* wp = lP[wave];
    const int swz = (c & 7);

#define STAGE(buf, kv0)                                                                     \
    do {                                                                                    \
        gld_lds16(kg + (size_t)((kv0) + r0) * 64 + ch0 * 8, (char*)kbuf[buf] + wave * 2048);            \
        gld_lds16(kg + (size_t)((kv0) + r1) * 64 + ch1 * 8, (char*)kbuf[buf] + wave * 2048 + 1024);     \
        gld_lds16(vg + (size_t)r0 * 1024 + (kv0) + ch0 * 8, (char*)vbuf[buf] + wave * 2048);            \
        gld_lds16(vg + (size_t)r1 * 1024 + (kv0) + ch1 * 8, (char*)vbuf[buf] + wave * 2048 + 1024);     \
    } while (0)

    STAGE(0, 0);
    __syncthreads();

    int cur = 0;
    for (int it = 0; it < 16; ++it) {
        const int kv0 = it * 64;
        if (it < 15) STAGE(cur ^ 1, kv0 + 64);
        float4 sws[4];
#pragma unroll
        for (int j = 0; j < 4; j++) sws[j] = *(const float4*)(swrow + kv0 + j * 16 + 4 * g);

        const char* kB = (const char*)kbuf[cur];
        const char* vB = (const char*)vbuf[cur];
#pragma unroll
        for (int ks2 = 0; ks2 < 2; ++ks2) {
            s16x8 kc0 = *(const s16x8*)(kB + ((ks2 * 32 + c) << 7) + (((0 + g) ^ swz) << 4));
            s16x8 kc1 = *(const s16x8*)(kB + ((ks2 * 32 + c) << 7) + (((4 + g) ^ swz) << 4));
            s16x8 kc2 = *(const s16x8*)(kB + ((ks2 * 32 + 16 + c) << 7) + (((0 + g) ^ swz) << 4));
            s16x8 kc3 = *(const s16x8*)(kB + ((ks2 * 32 + 16 + c) << 7) + (((4 + g) ^ swz) << 4));

            __builtin_amdgcn_s_setprio(1);
            f32x4 ss0 = {0.f, 0.f, 0.f, 0.f}, ss1 = {0.f, 0.f, 0.f, 0.f};
            ss0 = mfma16(kc0, qf0, ss0); ss0 = mfma16(kc1, qf1, ss0);
            ss1 = mfma16(kc2, qf0, ss1); ss1 = mfma16(kc3, qf1, ss1);
            __builtin_amdgcn_s_setprio(0);

            float4 swa = sws[2 * ks2], swb = sws[2 * ks2 + 1];
            float z0[4], z1[4];
#pragma unroll
            for (int r = 0; r < 4; r++) {
                z0[r] = ss0[r] * SC + (&swa.x)[r] * L2E;
                z1[r] = ss1[r] * SC + (&swb.x)[r] * L2E;
            }
            float tm = fmaxf(fmaxf(fmaxf(z0[0], z0[1]), fmaxf(z0[2], z0[3])),
                             fmaxf(fmaxf(z1[0], z1[1]), fmaxf(z1[2], z1[3])));
            tm = fmaxf(tm, __shfl_xor(tm, 16, 64));
            tm = fmaxf(tm, __shfl_xor(tm, 32, 64));

            // defer-max: only rescale when tile max exceeds budget (THR=8 bits)
            const bool need = __any((int)(tm > mr + 8.0f));
            float mn = mr, f = 1.0f;
            if (need) { mn = fmaxf(mr, tm); f = __builtin_amdgcn_exp2f(mr - mn); }

            float p0[4], p1[4];
#pragma unroll
            for (int r = 0; r < 4; r++) {
                p0[r] = __builtin_amdgcn_exp2f(z0[r] - mn);
                p1[r] = __builtin_amdgcn_exp2f(z1[r] - mn);
            }
            float rs = (p0[0] + p0[1]) + (p0[2] + p0[3]) + (p1[0] + p1[1]) + (p1[2] + p1[3]);
            rs += __shfl_xor(rs, 16, 64);
            rs += __shfl_xor(rs, 32, 64);

            if (need) {
                mr = mn;
                lr = lr * f + rs;
#pragma unroll
                for (int nf = 0; nf < 4; nf++)
#pragma unroll
                    for (int r = 0; r < 4; r++) acc[nf][r] *= f;
            } else {
                lr += rs;
            }

            // P -> LDS transpose: lane owns (q=c, k=4g..4g+3) and (q=c, k=16+4g..)
            u16x4 w0, w1;
#pragma unroll
            for (int r = 0; r < 4; r++) { w0[r] = f2bf(p0[r]); w1[r] = f2bf(p1[r]); }
            *(u16x4*)(wp + c * 40 + 4 * g) = w0;
            *(u16x4*)(wp + c * 40 + 16 + 4 * g) = w1;
            s16x8 ap = *(const s16x8*)((const char*)wp + c * 80 + g * 16);

            __builtin_amdgcn_s_setprio(1);
#pragma unroll
            for (int nf = 0; nf < 4; nf++) {
                s16x8 vf = *(const s16x8*)(vB + ((nf * 16 + c) << 7) + ((((ks2 << 2) + g) ^ swz) << 4));
                acc[nf] = mfma16(vf, ap, acc[nf]);       // ctx^T += V^T . P^T
            }
            __builtin_amdgcn_s_setprio(0);
        }
        __syncthreads();
        cur ^= 1;
    }
#undef STAGE

    // epilogue: normalize (lane-local), transpose ctx^T -> ctx via LDS scratch
    float inv = 1.0f / lr;
#pragma unroll
    for (int nf = 0; nf < 4; nf++)
#pragma unroll
        for (int r = 0; r < 4; r++) acc[nf][r] *= inv;

    __syncthreads();                                  // staging bufs now dead
    float* scr = (wave < 2) ? ((float*)kbuf + wave * 1088)
                            : ((float*)vbuf + (wave - 2) * 1088);   // 64 x 17 f32
#pragma unroll
    for (int nf = 0; nf < 4; nf++)
#pragma unroll
        for (int r = 0; r < 4; r++)
            scr[(nf * 16 + 4 * g + r) * 17 + c] = acc[nf][r];
    __syncthreads();
    u16x8 o0, o1;
#pragma unroll
    for (int j = 0; j < 8; j++) o0[j] = f2bf(scr[(g * 16 + j) * 17 + c]);
#pragma unroll
    for (int j = 0; j < 8; j++) o1[j] = f2bf(scr[(g * 16 + 8 + j) * 17 + c]);
    unsigned short* dst = ctx + ((size_t)(b_ << 10) + qr + c) * 1024 + (h << 6) + g * 16;
    *(u16x8*)dst = o0;
    *(u16x8*)(dst + 8) = o1;
}

// ------------------------------- launch ------------------------------------
extern "C" void kernel_launch(void* const* d_in, const int* in_sizes, int n_in,
                              void* d_out, int out_size, void* d_ws, size_t ws_size,
                              hipStream_t stream) {
    const float* x    = (const float*)d_in[0];
    const float* sb   = (const float*)d_in[1];
    const float* Wqkv = (const float*)d_in[2];
    const float* bqkv = (const float*)d_in[3];
    const float* Ws   = (const float*)d_in[4];
    const float* bs   = (const float*)d_in[5];
    const float* Wo   = (const float*)d_in[6];
    const float* bo   = (const float*)d_in[7];
    float* out = (float*)d_out;

    char* ws = (char*)d_ws;
    unsigned short* xb    = (unsigned short*)(ws);
    unsigned short* sbb   = (unsigned short*)(ws + ((size_t)4 << 20));
    unsigned short* wqkvt = (unsigned short*)(ws + ((size_t)8 << 20));
    unsigned short* wst   = (unsigned short*)(ws + ((size_t)14 << 20));
    unsigned short* wot   = (unsigned short*)(ws + ((size_t)16 << 20));
    unsigned short* qb    = (unsigned short*)(ws + ((size_t)18 << 20));
    unsigned short* kb    = (unsigned short*)(ws + ((size_t)22 << 20));
    unsigned short* vtb   = (unsigned short*)(ws + ((size_t)26 << 20));
    float*          swf   = (float*)        (ws + ((size_t)30 << 20));
    unsigned short* ctxb  = (unsigned short*)(ws + ((size_t)38 << 20));

    prep_k<<<dim3(3328), dim3(256), 0, stream>>>(x, sb, Wqkv, Ws, Wo,
                                                 xb, sbb, wqkvt, wst, wot);
    gemm_k<0><<<dim3(24, 32), dim3(256), 0, stream>>>(xb, wqkvt, bqkv, qb, kb, vtb, (float*)nullptr);
    gemm_k<1><<<dim3(8, 32), dim3(256), 0, stream>>>(sbb, wst, bs,
                                                     (unsigned short*)nullptr, (unsigned short*)nullptr,
                                                     (unsigned short*)nullptr, swf);
    attn_k<<<dim3(512), dim3(256), 0, stream>>>(qb, kb, vtb, swf, ctxb);
    gemm_k<1><<<dim3(8, 32), dim3(256), 0, stream>>>(ctxb, wot, bo,
                                                     (unsigned short*)nullptr, (unsigned short*)nullptr,
                                                     (unsigned short*)nullptr, out);
}